// Round 1
// baseline (244.077 us; speedup 1.0000x reference)
//
#include <hip/hip_runtime.h>
#include <hip/hip_bf16.h>
#include <math.h>

#define D_DIM 128
#define SIM_THR 0.2f
#define DEG_THR 3.0f
#define PT_THR 0.1
#define EPS_CS 1e-8

// ---------------- ws layout (bytes) ----------------
// [0,        400000)  c    : float[N]   (zeroed per call)
// [400000,   800000)  deg  : float[N]   (zeroed per call)
// [800000,  1200000)  inv0 : float[N]
// [1200000, 2000000)  na   : double[N]
// [2000000, 2000012)  flags: int[3]

// 32 lanes per node: inverse norm of raw x
__global__ void node_norm_kernel(const float* __restrict__ x,
                                 float* __restrict__ inv0, int N) {
    int g = threadIdx.x >> 5;
    int lane = threadIdx.x & 31;
    int n = blockIdx.x * 8 + g;
    if (n >= N) return;
    const float4 v = *(const float4*)(x + (size_t)n * D_DIM + lane * 4);
    double s = (double)v.x * v.x + (double)v.y * v.y + (double)v.z * v.z + (double)v.w * v.w;
    for (int m = 16; m; m >>= 1) s += __shfl_xor(s, m, 32);
    if (lane == 0) inv0[n] = 1.0f / (float)sqrt(s);
}

__global__ void prompt_flags_kernel(const float* __restrict__ ps,
                                    const float* __restrict__ pd,
                                    const float* __restrict__ po,
                                    int* __restrict__ flags) {
    if (threadIdx.x == 0) {
        int f0 = 1, f1 = 1, f2 = 1;
        for (int d = 0; d < D_DIM; ++d) {
            if (ps[d] == 0.0f) f0 = 0;
            if (pd[d] == 0.0f) f1 = 0;
            if (po[d] == 0.0f) f2 = 0;
        }
        flags[0] = f0; flags[1] = f1; flags[2] = f2;
    }
}

// 32 lanes per edge: e = cos(x[row], x[col]); scatter-add to c[col], deg[col]
__global__ void edge_sim_kernel(const float* __restrict__ x,
                                const int* __restrict__ ei,
                                const float* __restrict__ inv0,
                                float* __restrict__ c,
                                float* __restrict__ deg,
                                int E) {
    int g = threadIdx.x >> 5;
    int lane = threadIdx.x & 31;
    int e = blockIdx.x * 8 + g;
    if (e >= E) return;
    int row = ei[e];
    int col = ei[E + e];
    const float4 a = *(const float4*)(x + (size_t)row * D_DIM + lane * 4);
    const float4 b = *(const float4*)(x + (size_t)col * D_DIM + lane * 4);
    float dot = a.x * b.x + a.y * b.y + a.z * b.z + a.w * b.w;
    for (int m = 16; m; m >>= 1) dot += __shfl_xor(dot, m, 32);
    if (lane == 0) {
        float ev = dot * inv0[row] * inv0[col];
        atomicAdd(&c[col], ev);
        atomicAdd(&deg[col], 1.0f);
    }
}

// 32 lanes per node: masks -> final -> x_new; na = max(||x_new||, eps)
__global__ void node_prompt_kernel(const float* __restrict__ x,
                                   const float* __restrict__ c,
                                   const float* __restrict__ deg,
                                   const float* __restrict__ ps,
                                   const float* __restrict__ pd,
                                   const float* __restrict__ po,
                                   const int* __restrict__ flags,
                                   float* __restrict__ xn,
                                   double* __restrict__ na, int N) {
    int g = threadIdx.x >> 5;
    int lane = threadIdx.x & 31;
    int n = blockIdx.x * 8 + g;
    if (n >= N) return;
    float dg = deg[n];
    float cc = c[n];
    float csim = (dg > 0.0f) ? (cc / fmaxf(dg, 1.0f)) : INFINITY;
    bool ms = (csim <= SIM_THR);
    bool md = (dg <= DEG_THR);
    bool mo = !(ms || md);
    int plen = (ms && flags[0]) + (md && flags[1]) + (mo && flags[2]);
    float invp = (plen > 0) ? (1.0f / (float)plen) : 0.0f;

    int off = lane * 4;
    const float4 xv = *(const float4*)(x + (size_t)n * D_DIM + off);
    const float4 s  = *(const float4*)(ps + off);
    const float4 dd = *(const float4*)(pd + off);
    const float4 o  = *(const float4*)(po + off);

    float4 f;
    f.x = (ms ? s.x : 0.0f) + (md ? dd.x : 0.0f) + (mo ? o.x : 0.0f);
    f.y = (ms ? s.y : 0.0f) + (md ? dd.y : 0.0f) + (mo ? o.y : 0.0f);
    f.z = (ms ? s.z : 0.0f) + (md ? dd.z : 0.0f) + (mo ? o.z : 0.0f);
    f.w = (ms ? s.w : 0.0f) + (md ? dd.w : 0.0f) + (mo ? o.w : 0.0f);

    float4 r;
    r.x = xv.x + f.x * invp;
    r.y = xv.y + f.y * invp;
    r.z = xv.z + f.z * invp;
    r.w = xv.w + f.w * invp;

    *(float4*)(xn + (size_t)n * D_DIM + off) = r;

    double sq = (double)r.x * r.x + (double)r.y * r.y + (double)r.z * r.z + (double)r.w * r.w;
    for (int m = 16; m; m >>= 1) sq += __shfl_xor(sq, m, 32);
    if (lane == 0) {
        double nrm = sqrt(sq);
        na[n] = (nrm > EPS_CS) ? nrm : EPS_CS;
    }
}

// 32 lanes per edge: cos(x_new[row], x_new[col]) >= 0.1 (double accumulation)
__global__ void edge_prune_kernel(const float* __restrict__ xn,
                                  const int* __restrict__ ei,
                                  const double* __restrict__ na,
                                  float* __restrict__ keep, int E) {
    int g = threadIdx.x >> 5;
    int lane = threadIdx.x & 31;
    int e = blockIdx.x * 8 + g;
    if (e >= E) return;
    int row = ei[e];
    int col = ei[E + e];
    const float4 a = *(const float4*)(xn + (size_t)row * D_DIM + lane * 4);
    const float4 b = *(const float4*)(xn + (size_t)col * D_DIM + lane * 4);
    double dot = (double)a.x * b.x + (double)a.y * b.y + (double)a.z * b.z + (double)a.w * b.w;
    for (int m = 16; m; m >>= 1) dot += __shfl_xor(dot, m, 32);
    if (lane == 0) {
        double cos = dot / (na[row] * na[col]);
        keep[e] = (cos >= PT_THR) ? 1.0f : 0.0f;
    }
}

extern "C" void kernel_launch(void* const* d_in, const int* in_sizes, int n_in,
                              void* d_out, int out_size, void* d_ws, size_t ws_size,
                              hipStream_t stream) {
    const float* x  = (const float*)d_in[0];
    const int*   ei = (const int*)d_in[1];
    const float* ps = (const float*)d_in[2];
    const float* pd = (const float*)d_in[3];
    const float* po = (const float*)d_in[4];

    const int N = in_sizes[0] / D_DIM;    // 100000
    const int E = in_sizes[1] / 2;        // 640000

    char* ws = (char*)d_ws;
    float*  c_buf   = (float*)(ws + 0);
    float*  deg_buf = (float*)(ws + 400000);
    float*  inv0    = (float*)(ws + 800000);
    double* na      = (double*)(ws + 1200000);
    int*    flags   = (int*)(ws + 2000000);

    float* xn   = (float*)d_out;                       // [N, D]
    float* keep = (float*)d_out + (size_t)N * D_DIM;   // [E]

    hipMemsetAsync(c_buf, 0, 2 * 400000, stream);      // c + deg

    const int nodeBlocks = (N + 7) / 8;
    const int edgeBlocks = (E + 7) / 8;

    node_norm_kernel<<<nodeBlocks, 256, 0, stream>>>(x, inv0, N);
    prompt_flags_kernel<<<1, 64, 0, stream>>>(ps, pd, po, flags);
    edge_sim_kernel<<<edgeBlocks, 256, 0, stream>>>(x, ei, inv0, c_buf, deg_buf, E);
    node_prompt_kernel<<<nodeBlocks, 256, 0, stream>>>(x, c_buf, deg_buf, ps, pd, po,
                                                       flags, xn, na, N);
    edge_prune_kernel<<<edgeBlocks, 256, 0, stream>>>(xn, ei, na, keep, E);
}

// Round 2
// 215.029 us; speedup vs baseline: 1.1351x; 1.1351x over previous
//
#include <hip/hip_runtime.h>
#include <hip/hip_bf16.h>
#include <math.h>

#define D_DIM 128
#define SIM_THR 0.2f
#define DEG_THR 3.0f
#define PT_THR 0.1
#define EPS_CS 1e-8

typedef unsigned short u16;

// ---------------- ws layout (bytes) ----------------
// [0,        400000)  c    : float[N]   (zeroed per call)
// [400000,   800000)  deg  : float[N]   (zeroed per call)
// [800000,  1600000)  na   : double[N]
// [1600000, 1600012)  flags: int[3]
// xnorm (bf16, N*128*2 = 25.6MB) lives in d_out's x_new region (51.2MB),
// consumed by edge_sim before node_prompt overwrites it.

__device__ __forceinline__ float bf2f(u16 u) {
    return __uint_as_float(((unsigned)u) << 16);
}

// 32 lanes per node: normalize x (f32) and store bf16 row
__global__ void node_norm_kernel(const float* __restrict__ x,
                                 u16* __restrict__ xnorm, int N) {
    int g = threadIdx.x >> 5;
    int lane = threadIdx.x & 31;
    int n = blockIdx.x * 8 + g;
    if (n >= N) return;
    const float4 v = *(const float4*)(x + (size_t)n * D_DIM + lane * 4);
    float s = v.x * v.x + v.y * v.y + v.z * v.z + v.w * v.w;
    for (int m = 16; m; m >>= 1) s += __shfl_xor(s, m, 32);
    float inv = 1.0f / sqrtf(s);
    __hip_bfloat16 o[4];
    o[0] = __float2bfloat16(v.x * inv);
    o[1] = __float2bfloat16(v.y * inv);
    o[2] = __float2bfloat16(v.z * inv);
    o[3] = __float2bfloat16(v.w * inv);
    *(ushort4*)(xnorm + (size_t)n * D_DIM + lane * 4) =
        make_ushort4(*(u16*)&o[0], *(u16*)&o[1], *(u16*)&o[2], *(u16*)&o[3]);
}

__global__ void prompt_flags_kernel(const float* __restrict__ ps,
                                    const float* __restrict__ pd,
                                    const float* __restrict__ po,
                                    int* __restrict__ flags) {
    if (threadIdx.x == 0) {
        int f0 = 1, f1 = 1, f2 = 1;
        for (int d = 0; d < D_DIM; ++d) {
            if (ps[d] == 0.0f) f0 = 0;
            if (pd[d] == 0.0f) f1 = 0;
            if (po[d] == 0.0f) f2 = 0;
        }
        flags[0] = f0; flags[1] = f1; flags[2] = f2;
    }
}

// 32 lanes per 2 edges (4 row-loads in flight): bf16 gather, f32 dot
__global__ void edge_sim_kernel(const u16* __restrict__ xnorm,
                                const int* __restrict__ ei,
                                float* __restrict__ c,
                                float* __restrict__ deg,
                                int E) {
    int lane = threadIdx.x & 31;
    int grp = blockIdx.x * 8 + (threadIdx.x >> 5);
    int e0 = grp * 2, e1 = e0 + 1;
    if (e0 >= E) return;
    bool has1 = (e1 < E);
    int row0 = ei[e0], col0 = ei[E + e0];
    int row1 = has1 ? ei[e1] : row0;
    int col1 = has1 ? ei[E + e1] : col0;

    const ushort4 a0 = *(const ushort4*)(xnorm + (size_t)row0 * D_DIM + lane * 4);
    const ushort4 b0 = *(const ushort4*)(xnorm + (size_t)col0 * D_DIM + lane * 4);
    const ushort4 a1 = *(const ushort4*)(xnorm + (size_t)row1 * D_DIM + lane * 4);
    const ushort4 b1 = *(const ushort4*)(xnorm + (size_t)col1 * D_DIM + lane * 4);

    float d0 = bf2f(a0.x) * bf2f(b0.x) + bf2f(a0.y) * bf2f(b0.y) +
               bf2f(a0.z) * bf2f(b0.z) + bf2f(a0.w) * bf2f(b0.w);
    float d1 = bf2f(a1.x) * bf2f(b1.x) + bf2f(a1.y) * bf2f(b1.y) +
               bf2f(a1.z) * bf2f(b1.z) + bf2f(a1.w) * bf2f(b1.w);
    for (int m = 16; m; m >>= 1) {
        d0 += __shfl_xor(d0, m, 32);
        d1 += __shfl_xor(d1, m, 32);
    }
    if (lane == 0) {
        atomicAdd(&c[col0], d0);
        atomicAdd(&deg[col0], 1.0f);
    } else if (lane == 1 && has1) {
        atomicAdd(&c[col1], d1);
        atomicAdd(&deg[col1], 1.0f);
    }
}

// 32 lanes per node: masks -> final -> x_new; na = max(||x_new||, eps)
__global__ void node_prompt_kernel(const float* __restrict__ x,
                                   const float* __restrict__ c,
                                   const float* __restrict__ deg,
                                   const float* __restrict__ ps,
                                   const float* __restrict__ pd,
                                   const float* __restrict__ po,
                                   const int* __restrict__ flags,
                                   float* __restrict__ xn,
                                   double* __restrict__ na, int N) {
    int g = threadIdx.x >> 5;
    int lane = threadIdx.x & 31;
    int n = blockIdx.x * 8 + g;
    if (n >= N) return;
    float dg = deg[n];
    float cc = c[n];
    float csim = (dg > 0.0f) ? (cc / fmaxf(dg, 1.0f)) : INFINITY;
    bool ms = (csim <= SIM_THR);
    bool md = (dg <= DEG_THR);
    bool mo = !(ms || md);
    int plen = (ms && flags[0]) + (md && flags[1]) + (mo && flags[2]);
    float invp = (plen > 0) ? (1.0f / (float)plen) : 0.0f;

    int off = lane * 4;
    const float4 xv = *(const float4*)(x + (size_t)n * D_DIM + off);
    const float4 s  = *(const float4*)(ps + off);
    const float4 dd = *(const float4*)(pd + off);
    const float4 o  = *(const float4*)(po + off);

    float4 f;
    f.x = (ms ? s.x : 0.0f) + (md ? dd.x : 0.0f) + (mo ? o.x : 0.0f);
    f.y = (ms ? s.y : 0.0f) + (md ? dd.y : 0.0f) + (mo ? o.y : 0.0f);
    f.z = (ms ? s.z : 0.0f) + (md ? dd.z : 0.0f) + (mo ? o.z : 0.0f);
    f.w = (ms ? s.w : 0.0f) + (md ? dd.w : 0.0f) + (mo ? o.w : 0.0f);

    float4 r;
    r.x = xv.x + f.x * invp;
    r.y = xv.y + f.y * invp;
    r.z = xv.z + f.z * invp;
    r.w = xv.w + f.w * invp;

    *(float4*)(xn + (size_t)n * D_DIM + off) = r;

    double sq = (double)r.x * r.x + (double)r.y * r.y + (double)r.z * r.z + (double)r.w * r.w;
    for (int m = 16; m; m >>= 1) sq += __shfl_xor(sq, m, 32);
    if (lane == 0) {
        double nrm = sqrt(sq);
        na[n] = (nrm > EPS_CS) ? nrm : EPS_CS;
    }
}

// 32 lanes per 2 edges: cos(x_new[row], x_new[col]) >= 0.1 (f64 accumulate,
// per-edge math identical to the R0-passing version)
__global__ void edge_prune_kernel(const float* __restrict__ xn,
                                  const int* __restrict__ ei,
                                  const double* __restrict__ na,
                                  float* __restrict__ keep, int E) {
    int lane = threadIdx.x & 31;
    int grp = blockIdx.x * 8 + (threadIdx.x >> 5);
    int e0 = grp * 2, e1 = e0 + 1;
    if (e0 >= E) return;
    bool has1 = (e1 < E);
    int row0 = ei[e0], col0 = ei[E + e0];
    int row1 = has1 ? ei[e1] : row0;
    int col1 = has1 ? ei[E + e1] : col0;

    const float4 a0 = *(const float4*)(xn + (size_t)row0 * D_DIM + lane * 4);
    const float4 b0 = *(const float4*)(xn + (size_t)col0 * D_DIM + lane * 4);
    const float4 a1 = *(const float4*)(xn + (size_t)row1 * D_DIM + lane * 4);
    const float4 b1 = *(const float4*)(xn + (size_t)col1 * D_DIM + lane * 4);

    double d0 = (double)a0.x * b0.x + (double)a0.y * b0.y +
                (double)a0.z * b0.z + (double)a0.w * b0.w;
    double d1 = (double)a1.x * b1.x + (double)a1.y * b1.y +
                (double)a1.z * b1.z + (double)a1.w * b1.w;
    for (int m = 16; m; m >>= 1) {
        d0 += __shfl_xor(d0, m, 32);
        d1 += __shfl_xor(d1, m, 32);
    }
    if (lane == 0) {
        double cs = d0 / (na[row0] * na[col0]);
        keep[e0] = (cs >= PT_THR) ? 1.0f : 0.0f;
    } else if (lane == 1 && has1) {
        double cs = d1 / (na[row1] * na[col1]);
        keep[e1] = (cs >= PT_THR) ? 1.0f : 0.0f;
    }
}

extern "C" void kernel_launch(void* const* d_in, const int* in_sizes, int n_in,
                              void* d_out, int out_size, void* d_ws, size_t ws_size,
                              hipStream_t stream) {
    const float* x  = (const float*)d_in[0];
    const int*   ei = (const int*)d_in[1];
    const float* ps = (const float*)d_in[2];
    const float* pd = (const float*)d_in[3];
    const float* po = (const float*)d_in[4];

    const int N = in_sizes[0] / D_DIM;    // 100000
    const int E = in_sizes[1] / 2;        // 640000

    char* ws = (char*)d_ws;
    float*  c_buf   = (float*)(ws + 0);
    float*  deg_buf = (float*)(ws + 400000);
    double* na      = (double*)(ws + 800000);
    int*    flags   = (int*)(ws + 1600000);

    float* xn    = (float*)d_out;                       // [N, D]
    float* keep  = (float*)d_out + (size_t)N * D_DIM;   // [E]
    u16*   xnorm = (u16*)d_out;                         // bf16 [N, D], temp before xn overwrite

    hipMemsetAsync(c_buf, 0, 2 * 400000, stream);       // c + deg

    const int nodeBlocks = (N + 7) / 8;
    const int edgeBlocks = (E + 15) / 16;

    node_norm_kernel<<<nodeBlocks, 256, 0, stream>>>(x, xnorm, N);
    prompt_flags_kernel<<<1, 64, 0, stream>>>(ps, pd, po, flags);
    edge_sim_kernel<<<edgeBlocks, 256, 0, stream>>>(xnorm, ei, c_buf, deg_buf, E);
    node_prompt_kernel<<<nodeBlocks, 256, 0, stream>>>(x, c_buf, deg_buf, ps, pd, po,
                                                       flags, xn, na, N);
    edge_prune_kernel<<<edgeBlocks, 256, 0, stream>>>(xn, ei, na, keep, E);
}